// Round 7
// baseline (33607.489 us; speedup 1.0000x reference)
//
#include <hip/hip_runtime.h>
#include <math.h>

// Problem constants (match reference)
#define BB   32
#define LSEQ 512
#define DD   512
#define HH   512
#define G2H  1024
#define K3H  1536

// Scan: 8 groups x 64 WGs (group = blk&7; no placement assumption). Group g
// owns batch rows 4g..4g+3. WG slot s owns c/innov/K cols jz=8s..8s+7, kmid
// cols jm=24s..24s+23. 256 thr = 4 waves; wave q owns col quarter.
// Sync = wait-free tag dataflow: producer publishes data (sc0sc1 stores),
// waitcnt+syncthreads, then bumps its packed per-slot tag; consumers poll the
// 64-u32 packed tag array (4 cache lines) until >= wanted generation, then
// cooperatively sc1-stage the comm vectors into LDS once per WG.
#define NG   8
#define GWG  64

typedef unsigned int u32;
typedef _Float16 half2_t __attribute__((ext_vector_type(2)));
typedef u32 v4u __attribute__((ext_vector_type(4)));

// ---- coherence-point memory ops ----
__device__ __forceinline__ void mload4(v4u& d, const u32* p) {
  asm volatile("global_load_dwordx4 %0, %1, off sc1" : "=v"(d) : "v"(p));
}
__device__ __forceinline__ void mstore(u32* p, u32 v) {
  asm volatile("global_store_dword %0, %1, off sc0 sc1" :: "v"(p), "v"(v)
               : "memory");
}

__device__ __forceinline__ float dot2acc(u32 a, u32 b, float acc) {
#if __has_builtin(__builtin_amdgcn_fdot2)
  return __builtin_amdgcn_fdot2(__builtin_bit_cast(half2_t, a),
                                __builtin_bit_cast(half2_t, b), acc, false);
#else
  half2_t ha = __builtin_bit_cast(half2_t, a);
  half2_t hb = __builtin_bit_cast(half2_t, b);
  return acc + (float)ha[0] * (float)hb[0] + (float)ha[1] * (float)hb[1];
#endif
}
__device__ __forceinline__ float dotq(v4u a, v4u b, float acc) {
  acc = dot2acc(a.x, b.x, acc);
  acc = dot2acc(a.y, b.y, acc);
  acc = dot2acc(a.z, b.z, acc);
  acc = dot2acc(a.w, b.w, acc);
  return acc;
}
__device__ __forceinline__ u32 pkf16(float a, float b) {
#if __has_builtin(__builtin_amdgcn_cvt_pkrtz)
  return __builtin_bit_cast(u32, __builtin_amdgcn_cvt_pkrtz(a, b));
#else
  half2_t h; h[0] = (_Float16)a; h[1] = (_Float16)b;
  return __builtin_bit_cast(u32, h);
#endif
}

// In-register shuffle reduction trees (value for index lane&(M-1)).
template<int M> struct TreeC {
  static __device__ __forceinline__ void run(float* a, int lane, int d) {
    const bool hi = (lane & d) != 0;
#pragma unroll
    for (int i = 0; i < M / 2; ++i) {
      float mine  = hi ? a[2 * i + 1] : a[2 * i];
      float yours = hi ? a[2 * i]     : a[2 * i + 1];
      a[i] = mine + __shfl_xor(yours, d, 64);
    }
    TreeC<M / 2>::run(a, lane, d << 1);
  }
};
template<> struct TreeC<1> {
  static __device__ __forceinline__ void run(float*, int, int) {}
};
template<int M>
__device__ __forceinline__ float tree_reduce(float* a, int lane) {
  TreeC<M>::run(a, lane, 1);
  float v = a[0];
#pragma unroll
  for (int d = M; d <= 32; d <<= 1) v += __shfl_xor(v, d, 64);
  return v;
}

// poll packed group tags (64 u32 = 4 lines); every wave polls all 64
__device__ __forceinline__ void poll_tags(const u32* tgg, u32 want, int tid) {
  const u32* tp = tgg + (tid & 63);
  while (__hip_atomic_load(tp, __ATOMIC_RELAXED,
                           __HIP_MEMORY_SCOPE_AGENT) < want) {}
}

// drain this wave's outstanding global stores, then WG-sync
__device__ __forceinline__ void publish_fence() {
  asm volatile("s_waitcnt vmcnt(0)" ::: "memory");
  __syncthreads();
}

// ---------------------------------------------------------------------------
// RMSNorm: one 256-thread WG per row of 512.
// ---------------------------------------------------------------------------
__global__ __launch_bounds__(256)
void rmsnorm_kernel(const float* __restrict__ x, const float* __restrict__ w,
                    float* __restrict__ y)
{
  __shared__ float redl[256];
  const long row = blockIdx.x;
  const int t = threadIdx.x;
  const float* xr = x + row * DD;
  float v0 = xr[t], v1 = xr[t + 256];
  redl[t] = v0 * v0 + v1 * v1;
  __syncthreads();
  for (int off = 128; off > 0; off >>= 1) {
    if (t < off) redl[t] += redl[t + off];
    __syncthreads();
  }
  float scale = rsqrtf(redl[0] * (1.0f / 512.0f) + 1e-5f);
  float* yr = y + row * DD;
  yr[t]       = v0 * scale * w[t];
  yr[t + 256] = v1 * scale * w[t + 256];
}

// ---------------------------------------------------------------------------
// fp32 tiled GEMM: C[M,N] = A[M,K] @ B[K,N] (+ bias[n]), all row-major.
// ---------------------------------------------------------------------------
__global__ __launch_bounds__(256)
void gemm_fp32(const float* __restrict__ A, const float* __restrict__ B,
               const float* __restrict__ bias, float* __restrict__ C,
               int M, int N, int K)
{
  __shared__ float As[16][68];
  __shared__ float Bs[16][64];
  const int t  = threadIdx.x;
  const int tx = t & 15, ty = t >> 4;
  const long m0 = (long)blockIdx.x * 64;
  const long n0 = (long)blockIdx.y * 64;
  const int ar = t >> 2, ac = (t & 3) * 4;
  const int bk = t >> 4, bn = (t & 15) * 4;
  float acc[4][4] = {{0.f}};

  for (int k0 = 0; k0 < K; k0 += 16) {
    float4 av = *(const float4*)(A + (m0 + ar) * K + k0 + ac);
    float4 bv = *(const float4*)(B + (long)(k0 + bk) * N + n0 + bn);
    As[ac + 0][ar] = av.x; As[ac + 1][ar] = av.y;
    As[ac + 2][ar] = av.z; As[ac + 3][ar] = av.w;
    *(float4*)&Bs[bk][bn] = bv;
    __syncthreads();
#pragma unroll
    for (int kk = 0; kk < 16; ++kk) {
      float4 a = *(const float4*)&As[kk][ty * 4];
      float4 b = *(const float4*)&Bs[kk][tx * 4];
      acc[0][0] = fmaf(a.x, b.x, acc[0][0]); acc[0][1] = fmaf(a.x, b.y, acc[0][1]);
      acc[0][2] = fmaf(a.x, b.z, acc[0][2]); acc[0][3] = fmaf(a.x, b.w, acc[0][3]);
      acc[1][0] = fmaf(a.y, b.x, acc[1][0]); acc[1][1] = fmaf(a.y, b.y, acc[1][1]);
      acc[1][2] = fmaf(a.y, b.z, acc[1][2]); acc[1][3] = fmaf(a.y, b.w, acc[1][3]);
      acc[2][0] = fmaf(a.z, b.x, acc[2][0]); acc[2][1] = fmaf(a.z, b.y, acc[2][1]);
      acc[2][2] = fmaf(a.z, b.z, acc[2][2]); acc[2][3] = fmaf(a.z, b.w, acc[2][3]);
      acc[3][0] = fmaf(a.w, b.x, acc[3][0]); acc[3][1] = fmaf(a.w, b.y, acc[3][1]);
      acc[3][2] = fmaf(a.w, b.z, acc[3][2]); acc[3][3] = fmaf(a.w, b.w, acc[3][3]);
    }
    __syncthreads();
  }
  float4 bb = make_float4(0.f, 0.f, 0.f, 0.f);
  if (bias) bb = *(const float4*)(bias + n0 + tx * 4);
#pragma unroll
  for (int i = 0; i < 4; ++i) {
    float4 o;
    o.x = acc[i][0] + bb.x; o.y = acc[i][1] + bb.y;
    o.z = acc[i][2] + bb.z; o.w = acc[i][3] + bb.w;
    *(float4*)(C + (m0 + ty * 4 + i) * N + n0 + tx * 4) = o;
  }
}

// ---------------------------------------------------------------------------
// Prep: pack kW2 (fp32 [1536][512]) into f16 pairs laid out per-slot:
// kw2p[(8s+ci)*768 + p] = (kW2[2p][8s+ci], kW2[2p+1][8s+ci]).
// ---------------------------------------------------------------------------
__global__ __launch_bounds__(256)
void pack_kw2(const float* __restrict__ kW2, u32* __restrict__ kw2p)
{
  int idx = blockIdx.x * 256 + threadIdx.x;   // < 512*768
  int p   = idx % 768;
  int col = idx / 768;                        // 0..511
  kw2p[idx] = pkf16(kW2[(size_t)(2 * p) * HH + col],
                    kW2[(size_t)(2 * p + 1) * HH + col]);
}

// ---------------------------------------------------------------------------
// Persistent scan: 512 WGs x 256 thr, 52 KB static LDS.
// ---------------------------------------------------------------------------
__global__ __launch_bounds__(256)
void scan_kernel(const float* __restrict__ gx,
                 const float* __restrict__ Whh, const float* __restrict__ bhh,
                 const float* __restrict__ loglam,
                 const float* __restrict__ kW1, const float* __restrict__ kb1,
                 const u32* __restrict__ kw2p, const float* __restrict__ kb2,
                 u32* __restrict__ cpk, u32* __restrict__ ipk,
                 u32* __restrict__ kpk, u32* __restrict__ tags,
                 float* __restrict__ hs)
{
  const int blk  = blockIdx.x;
  const int g    = blk & 7;         // group (rows 4g..4g+3)
  const int s    = blk >> 3;        // slot 0..63
  const int tid  = threadIdx.x;
  const int q    = tid >> 6;        // wave 0..3
  const int lane = tid & 63;
  const int jz   = s * 8;
  const int jm   = s * 24;

  __shared__ u32 wh[16 * 256];      // 16 KB: 8 z-cols + 8 m-cols, f16 pairs
  __shared__ u32 w1s[24 * 256];     // 24 KB
  __shared__ u32 stg[4 * 768];      // 12 KB comm staging (c/innov use 1/3)

  // ---- one-time weight staging (fp32 -> f16 pairs) ----
  for (int idx = tid; idx < 16 * 256; idx += 256) {
    int c = idx >> 8, p = idx & 255;
    int gcol = (c < 8) ? (jz + c) : (512 + jz + (c - 8));
    wh[idx] = pkf16(Whh[(size_t)(2 * p) * G2H + gcol],
                    Whh[(size_t)(2 * p + 1) * G2H + gcol]);
  }
  for (int idx = tid; idx < 24 * 256; idx += 256) {
    int c = idx >> 8, p = idx & 255;
    w1s[idx] = pkf16(kW1[(size_t)(2 * p) * K3H + jm + c],
                     kW1[(size_t)(2 * p + 1) * K3H + jm + c]);
  }

  // per-lane constants (state mapping: r=lane>>1, ci=lane&1, valid lanes<8)
  const int colA = jz + 2 * q + (lane & 1);
  const float Ab   = 1.f - expf(loglam[colA]);
  const float bz   = bhh[colA];
  const float bm   = bhh[512 + colA];
  const float kb2c = kb2[colA];
  int kb1i = lane & 7; if (kb1i > 5) kb1i = 5;
  const float kb1v = kb1[jm + 6 * q + kb1i];

  const int r_st  = (lane >> 1) & 3;
  const int growst = 4 * g + r_st;
  const size_t hsoff = (size_t)growst * LSEQ * HH + colA;
  const size_t gxoff = (size_t)growst * LSEQ * G2H + colA;

  u32* tgg = tags + g * GWG;

  // zero this WG's initial c slice, then publish tag gen 1
  if (tid < 16) {
    int r = tid >> 2, j = tid & 3;
    mstore(cpk + (size_t)(4 * g + r) * 256 + 4 * s + j, 0u);
  }
  publish_fence();
  if (tid == 0) mstore(tgg + s, 1u);

  float A_own = 0.f, c_own = 0.f, M_own = 0.f, I_own = 0.f, s_own = 1.f;

  for (int it = 0; it <= LSEQ; ++it) {
    const u32 base = 3u * (u32)it;

    // gx prefetch (cached, read-once; independent of polls)
    float gxz = 0.f, gxm = 0.f;
    if (lane < 8 && it < LSEQ) {
      gxz = gx[gxoff + (size_t)it * G2H];
      gxm = gx[gxoff + (size_t)it * G2H + 512];
    }

    // ---- S1: wait c(it) -> stage -> s, g = h@W_hh, innov ----
    poll_tags(tgg, base + 1, tid);
    {
      int row = tid >> 6, off = (tid & 63) * 4;
      v4u t; mload4(t, cpk + (size_t)(4 * g + row) * 256 + off);
      asm volatile("s_waitcnt vmcnt(0)" ::: "memory");
      *(v4u*)(stg + row * 256 + off) = t;
    }
    __syncthreads();
    v4u cv0 = *(const v4u*)(stg + 0 * 256 + lane * 4);
    v4u cv1 = *(const v4u*)(stg + 1 * 256 + lane * 4);
    v4u cv2 = *(const v4u*)(stg + 2 * 256 + lane * 4);
    v4u cv3 = *(const v4u*)(stg + 3 * 256 + lane * 4);
    float a4[4] = { dotq(cv0, cv0, 0.f), dotq(cv1, cv1, 0.f),
                    dotq(cv2, cv2, 0.f), dotq(cv3, cv3, 0.f) };
    float a16[16];
#pragma unroll
    for (int t = 0; t < 4; ++t) {          // t<2: z col 2q+t ; t>=2: m col
      int col = (t < 2) ? (2 * q + t) : (8 + 2 * q + (t - 2));
      v4u wq = *(const v4u*)(wh + col * 256 + lane * 4);
      a16[0 * 4 + t] = dotq(cv0, wq, 0.f);
      a16[1 * 4 + t] = dotq(cv1, wq, 0.f);
      a16[2 * 4 + t] = dotq(cv2, wq, 0.f);
      a16[3 * 4 + t] = dotq(cv3, wq, 0.f);
    }
    float ssv = tree_reduce<4>(a4, lane);     // row = lane&3
    float g16 = tree_reduce<16>(a16, lane);   // (r=(lane&15)>>2, t=lane&3)
    float sq  = __shfl(ssv, r_st, 64);
    float s_loc = fminf(1.f, 10.f * rsqrtf(sq + 1e-6f));
    float gz = __shfl(g16, (r_st * 4 + (lane & 1)) & 63, 64);
    float gm = __shfl(g16, (r_st * 4 + 2 + (lane & 1)) & 63, 64);
    if (lane < 8 && it >= 1)
      hs[hsoff + (size_t)(it - 1) * HH] = s_loc * c_own;
    if (it == LSEQ) break;
    float gzv = gz * s_loc + gxz + bz;
    float gmv = gm * s_loc + gxm + bm;
    float Mv = tanhf(gmv);
    float iv = gzv - A_own * (s_loc * c_own) - Mv;
    if (lane < 8) { M_own = Mv; I_own = iv; s_own = s_loc; }
    float ivn = __shfl(iv, (lane + 1) & 63, 64);
    if (lane < 8 && !(lane & 1))
      mstore(ipk + (size_t)growst * 256 + 4 * s + q, pkf16(iv, ivn));
    publish_fence();
    if (tid == 0) mstore(tgg + s, base + 2);

    // ---- S2: wait innov -> stage -> kmid = gelu(innov @ kW1 + kb1) ----
    poll_tags(tgg, base + 2, tid);
    {
      int row = tid >> 6, off = (tid & 63) * 4;
      v4u t; mload4(t, ipk + (size_t)(4 * g + row) * 256 + off);
      asm volatile("s_waitcnt vmcnt(0)" ::: "memory");
      *(v4u*)(stg + row * 256 + off) = t;
    }
    __syncthreads();
    v4u iv0 = *(const v4u*)(stg + 0 * 256 + lane * 4);
    v4u iv1 = *(const v4u*)(stg + 1 * 256 + lane * 4);
    v4u iv2 = *(const v4u*)(stg + 2 * 256 + lane * 4);
    v4u iv3 = *(const v4u*)(stg + 3 * 256 + lane * 4);
    float a32[32];
#pragma unroll
    for (int i = 0; i < 32; ++i) a32[i] = 0.f;
#pragma unroll
    for (int cc = 0; cc < 6; ++cc) {
      v4u wq = *(const v4u*)(w1s + (6 * q + cc) * 256 + lane * 4);
      a32[0 * 8 + cc] = dotq(iv0, wq, 0.f);
      a32[1 * 8 + cc] = dotq(iv1, wq, 0.f);
      a32[2 * 8 + cc] = dotq(iv2, wq, 0.f);
      a32[3 * 8 + cc] = dotq(iv3, wq, 0.f);
    }
    float t32 = tree_reduce<32>(a32, lane);   // (r=(lane&31)>>3, cc=lane&7)
    float kvb = t32 + kb1v;
    float gl = 0.5f * kvb * (1.f + erff(kvb * 0.7071067811865476f));
    float gln = __shfl(gl, (lane + 1) & 63, 64);
    if (lane < 32 && !(lane & 1) && (lane & 7) < 6) {
      int rr = (lane >> 3) & 3, cc = lane & 7;
      mstore(kpk + (size_t)(4 * g + rr) * 768 + 12 * s + 3 * q + (cc >> 1),
             pkf16(gl, gln));
    }
    publish_fence();
    if (tid == 0) mstore(tgg + s, base + 3);

    // ---- S3: wait kmid -> stage -> K = tanh(kmid @ kW2 + kb2)*0.5 ; c ----
    poll_tags(tgg, base + 3, tid);
    {
      int row = tid >> 6, off = (tid & 63) * 4;
      const u32* src = kpk + (size_t)(4 * g + row) * 768 + off;
      v4u t0, t1, t2;
      mload4(t0, src); mload4(t1, src + 256); mload4(t2, src + 512);
      asm volatile("s_waitcnt vmcnt(0)" ::: "memory");
      u32* dst = stg + row * 768 + off;
      *(v4u*)dst = t0; *(v4u*)(dst + 256) = t1; *(v4u*)(dst + 512) = t2;
    }
    __syncthreads();
    v4u kv[4][3];
#pragma unroll
    for (int r = 0; r < 4; ++r)
#pragma unroll
      for (int j = 0; j < 3; ++j)
        kv[r][j] = *(const v4u*)(stg + r * 768 + j * 256 + lane * 4);
    const u32* kw2b = kw2p + (size_t)(8 * s + 2 * q) * 768;
    float a8[8];
#pragma unroll
    for (int ci = 0; ci < 2; ++ci) {
      v4u wq0 = *(const v4u*)(kw2b + ci * 768 + 0   + lane * 4);
      v4u wq1 = *(const v4u*)(kw2b + ci * 768 + 256 + lane * 4);
      v4u wq2 = *(const v4u*)(kw2b + ci * 768 + 512 + lane * 4);
#pragma unroll
      for (int r = 0; r < 4; ++r)
        a8[r * 2 + ci] = dotq(kv[r][2], wq2,
                         dotq(kv[r][1], wq1,
                         dotq(kv[r][0], wq0, 0.f)));
    }
    float kr = tree_reduce<8>(a8, lane);   // (r=(lane&7)>>1, ci=lane&1)
    float Kv = tanhf(kr + kb2c) * 0.5f;
    float An = Ab * (1.f - Kv * Kv);
    float cn = An * (s_own * c_own) + Kv * I_own + M_own;
    if (lane < 8) { A_own = An; c_own = cn; }
    float cnn = __shfl(cn, (lane + 1) & 63, 64);
    if (lane < 8 && !(lane & 1))
      mstore(cpk + (size_t)growst * 256 + 4 * s + q, pkf16(cn, cnn));
    publish_fence();
    if (tid == 0) mstore(tgg + s, base + 4);
  }
}

// ---------------------------------------------------------------------------
// Workspace layout (bytes):
//   [0, 32M)    xn (reused as hs)
//   [32M, 96M)  gx
//   [96M,128M)  xmid  (first 1.5MB doubles as kw2p — dead during scans)
//   [128M, ..)  cpk 32K | ipk 32K | kpk 96K | tags 2K
// ---------------------------------------------------------------------------
extern "C" void kernel_launch(void* const* d_in, const int* in_sizes, int n_in,
                              void* d_out, int out_size, void* d_ws, size_t ws_size,
                              hipStream_t stream) {
  const float* x      = (const float*)d_in[0];
  const float* norm_w = (const float*)d_in[1];
  const float* W_ih   = (const float*)d_in[2];
  const float* b_ih   = (const float*)d_in[3];
  const float* W_hh   = (const float*)d_in[4];
  const float* b_hh   = (const float*)d_in[5];
  const float* loglam = (const float*)d_in[6];
  const float* kW1    = (const float*)d_in[7];
  const float* kb1    = (const float*)d_in[8];
  const float* kW2    = (const float*)d_in[9];
  const float* kb2    = (const float*)d_in[10];
  const float* Wo     = (const float*)d_in[11];
  float* out = (float*)d_out;

  char* ws = (char*)d_ws;
  float* xn   = (float*)(ws);
  float* gxb  = (float*)(ws + (size_t)33554432);
  float* xmid = (float*)(ws + (size_t)100663296);
  u32* kw2p  = (u32*)xmid;              // 1.5MB, dead region during scans
  u32* cpk   = (u32*)(ws + (size_t)134217728);
  u32* ipk   = cpk + 8192;
  u32* kpk   = ipk + 8192;
  u32* tags  = kpk + 24576;             // 512 u32
  float* hs = xn;

  for (int l = 0; l < 2; ++l) {
    const float* xin = l ? (const float*)xmid : x;
    float* cout = l ? out : xmid;

    rmsnorm_kernel<<<BB * LSEQ, 256, 0, stream>>>(xin, norm_w, xn);

    gemm_fp32<<<dim3(256, 16), 256, 0, stream>>>(
        xn, W_ih + (size_t)l * DD * G2H, b_ih + (size_t)l * G2H, gxb,
        BB * LSEQ, G2H, DD);

    hipMemsetAsync(tags, 0, NG * GWG * sizeof(u32), stream);
    pack_kw2<<<1536, 256, 0, stream>>>(kW2 + (size_t)l * K3H * HH, kw2p);

    scan_kernel<<<NG * GWG, 256, 0, stream>>>(
        gxb,
        W_hh + (size_t)l * HH * G2H, b_hh + (size_t)l * G2H,
        loglam + (size_t)l * HH,
        kW1 + (size_t)l * HH * K3H, kb1 + (size_t)l * K3H,
        kw2p, kb2 + (size_t)l * HH,
        cpk, ipk, kpk, tags, hs);

    gemm_fp32<<<dim3(256, 8), 256, 0, stream>>>(
        hs, Wo + (size_t)l * HH * DD, nullptr, cout,
        BB * LSEQ, DD, HH);
  }
}

// Round 8
// 15218.271 us; speedup vs baseline: 2.2084x; 2.2084x over previous
//
#include <hip/hip_runtime.h>
#include <math.h>

// Problem constants (match reference)
#define BB   32
#define LSEQ 512
#define DD   512
#define HH   512
#define G2H  1024
#define K3H  1536

// Scan: 8 groups x 64 WGs (group = blk&7; no placement assumption). Group g
// owns batch rows 4g..4g+3. WG slot s owns c/innov/K cols jz=8s..8s+7, kmid
// cols jm=24s..24s+23. 256 thr = 4 waves; wave q owns col quarter.
// Sync: ONE-HOP packed-tag barrier. Producer publishes data (sc0sc1 stores),
// drains vmcnt + syncthreads, then stores tags[g*64+s]=gen (packed 4 lines/
// group, distinct addresses -> no RMW serialization). Consumers: lanes 0..15
// of wave 0 each poll one dwordx4 (16 tags) until min >= gen. Poller census:
// 16/WG x 512 WGs = 8k pollers x 16B ~ 130 GB/s — R6's proven-safe regime
// (R7's 131k pollers = MALL storm; R3's 33k = storm. ~1k..8k = clean).
#define NG   8
#define GWG  64

typedef unsigned int u32;
typedef _Float16 half2_t __attribute__((ext_vector_type(2)));
typedef u32 v4u __attribute__((ext_vector_type(4)));

// ---- coherence-point memory ops ----
__device__ __forceinline__ void mload4(v4u& d, const u32* p) {
  asm volatile("global_load_dwordx4 %0, %1, off sc1" : "=v"(d) : "v"(p));
}
__device__ __forceinline__ void mstore(u32* p, u32 v) {
  asm volatile("global_store_dword %0, %1, off sc0 sc1" :: "v"(p), "v"(v)
               : "memory");
}
// waitcnt that TIES a loaded reg so uses can't be scheduled before it
__device__ __forceinline__ void vmwait(v4u& a) {
  asm volatile("s_waitcnt vmcnt(0)" : "+v"(a) :: "memory");
}

__device__ __forceinline__ float dot2acc(u32 a, u32 b, float acc) {
#if __has_builtin(__builtin_amdgcn_fdot2)
  return __builtin_amdgcn_fdot2(__builtin_bit_cast(half2_t, a),
                                __builtin_bit_cast(half2_t, b), acc, false);
#else
  half2_t ha = __builtin_bit_cast(half2_t, a);
  half2_t hb = __builtin_bit_cast(half2_t, b);
  return acc + (float)ha[0] * (float)hb[0] + (float)ha[1] * (float)hb[1];
#endif
}
__device__ __forceinline__ float dotq(v4u a, v4u b, float acc) {
  acc = dot2acc(a.x, b.x, acc);
  acc = dot2acc(a.y, b.y, acc);
  acc = dot2acc(a.z, b.z, acc);
  acc = dot2acc(a.w, b.w, acc);
  return acc;
}
__device__ __forceinline__ u32 pkf16(float a, float b) {
#if __has_builtin(__builtin_amdgcn_cvt_pkrtz)
  return __builtin_bit_cast(u32, __builtin_amdgcn_cvt_pkrtz(a, b));
#else
  half2_t h; h[0] = (_Float16)a; h[1] = (_Float16)b;
  return __builtin_bit_cast(u32, h);
#endif
}

// In-register shuffle reduction trees (value for index lane&(M-1)).
template<int M> struct TreeC {
  static __device__ __forceinline__ void run(float* a, int lane, int d) {
    const bool hi = (lane & d) != 0;
#pragma unroll
    for (int i = 0; i < M / 2; ++i) {
      float mine  = hi ? a[2 * i + 1] : a[2 * i];
      float yours = hi ? a[2 * i]     : a[2 * i + 1];
      a[i] = mine + __shfl_xor(yours, d, 64);
    }
    TreeC<M / 2>::run(a, lane, d << 1);
  }
};
template<> struct TreeC<1> {
  static __device__ __forceinline__ void run(float*, int, int) {}
};
template<int M>
__device__ __forceinline__ float tree_reduce(float* a, int lane) {
  TreeC<M>::run(a, lane, 1);
  float v = a[0];
#pragma unroll
  for (int d = M; d <= 32; d <<= 1) v += __shfl_xor(v, d, 64);
  return v;
}

// one-hop barrier wait: 16 pollers (lanes 0..15 of wave 0), 16 tags each
__device__ __forceinline__ void poll16(const u32* tgg, u32 want, int tid) {
  if (tid < 16) {
    const u32* p = tgg + tid * 4;
    for (;;) {
      v4u t; mload4(t, p);
      vmwait(t);
      u32 m0 = t.x < t.y ? t.x : t.y;
      u32 m1 = t.z < t.w ? t.z : t.w;
      if ((m0 < m1 ? m0 : m1) >= want) break;
    }
  }
  __syncthreads();
}

// drain this wave's outstanding global stores, then WG-sync
__device__ __forceinline__ void publish_fence() {
  asm volatile("s_waitcnt vmcnt(0)" ::: "memory");
  __syncthreads();
}

// ---------------------------------------------------------------------------
// RMSNorm: one 256-thread WG per row of 512.
// ---------------------------------------------------------------------------
__global__ __launch_bounds__(256)
void rmsnorm_kernel(const float* __restrict__ x, const float* __restrict__ w,
                    float* __restrict__ y)
{
  __shared__ float redl[256];
  const long row = blockIdx.x;
  const int t = threadIdx.x;
  const float* xr = x + row * DD;
  float v0 = xr[t], v1 = xr[t + 256];
  redl[t] = v0 * v0 + v1 * v1;
  __syncthreads();
  for (int off = 128; off > 0; off >>= 1) {
    if (t < off) redl[t] += redl[t + off];
    __syncthreads();
  }
  float scale = rsqrtf(redl[0] * (1.0f / 512.0f) + 1e-5f);
  float* yr = y + row * DD;
  yr[t]       = v0 * scale * w[t];
  yr[t + 256] = v1 * scale * w[t + 256];
}

// ---------------------------------------------------------------------------
// fp32 tiled GEMM: C[M,N] = A[M,K] @ B[K,N] (+ bias[n]), all row-major.
// ---------------------------------------------------------------------------
__global__ __launch_bounds__(256)
void gemm_fp32(const float* __restrict__ A, const float* __restrict__ B,
               const float* __restrict__ bias, float* __restrict__ C,
               int M, int N, int K)
{
  __shared__ float As[16][68];
  __shared__ float Bs[16][64];
  const int t  = threadIdx.x;
  const int tx = t & 15, ty = t >> 4;
  const long m0 = (long)blockIdx.x * 64;
  const long n0 = (long)blockIdx.y * 64;
  const int ar = t >> 2, ac = (t & 3) * 4;
  const int bk = t >> 4, bn = (t & 15) * 4;
  float acc[4][4] = {{0.f}};

  for (int k0 = 0; k0 < K; k0 += 16) {
    float4 av = *(const float4*)(A + (m0 + ar) * K + k0 + ac);
    float4 bv = *(const float4*)(B + (long)(k0 + bk) * N + n0 + bn);
    As[ac + 0][ar] = av.x; As[ac + 1][ar] = av.y;
    As[ac + 2][ar] = av.z; As[ac + 3][ar] = av.w;
    *(float4*)&Bs[bk][bn] = bv;
    __syncthreads();
#pragma unroll
    for (int kk = 0; kk < 16; ++kk) {
      float4 a = *(const float4*)&As[kk][ty * 4];
      float4 b = *(const float4*)&Bs[kk][tx * 4];
      acc[0][0] = fmaf(a.x, b.x, acc[0][0]); acc[0][1] = fmaf(a.x, b.y, acc[0][1]);
      acc[0][2] = fmaf(a.x, b.z, acc[0][2]); acc[0][3] = fmaf(a.x, b.w, acc[0][3]);
      acc[1][0] = fmaf(a.y, b.x, acc[1][0]); acc[1][1] = fmaf(a.y, b.y, acc[1][1]);
      acc[1][2] = fmaf(a.y, b.z, acc[1][2]); acc[1][3] = fmaf(a.y, b.w, acc[1][3]);
      acc[2][0] = fmaf(a.z, b.x, acc[2][0]); acc[2][1] = fmaf(a.z, b.y, acc[2][1]);
      acc[2][2] = fmaf(a.z, b.z, acc[2][2]); acc[2][3] = fmaf(a.z, b.w, acc[2][3]);
      acc[3][0] = fmaf(a.w, b.x, acc[3][0]); acc[3][1] = fmaf(a.w, b.y, acc[3][1]);
      acc[3][2] = fmaf(a.w, b.z, acc[3][2]); acc[3][3] = fmaf(a.w, b.w, acc[3][3]);
    }
    __syncthreads();
  }
  float4 bb = make_float4(0.f, 0.f, 0.f, 0.f);
  if (bias) bb = *(const float4*)(bias + n0 + tx * 4);
#pragma unroll
  for (int i = 0; i < 4; ++i) {
    float4 o;
    o.x = acc[i][0] + bb.x; o.y = acc[i][1] + bb.y;
    o.z = acc[i][2] + bb.z; o.w = acc[i][3] + bb.w;
    *(float4*)(C + (m0 + ty * 4 + i) * N + n0 + tx * 4) = o;
  }
}

// ---------------------------------------------------------------------------
// Prep: pack kW2 (fp32 [1536][512]) into f16 pairs laid out per-slot:
// kw2p[(8s+ci)*768 + p] = (kW2[2p][8s+ci], kW2[2p+1][8s+ci]).
// ---------------------------------------------------------------------------
__global__ __launch_bounds__(256)
void pack_kw2(const float* __restrict__ kW2, u32* __restrict__ kw2p)
{
  int idx = blockIdx.x * 256 + threadIdx.x;   // < 512*768
  int p   = idx % 768;
  int col = idx / 768;                        // 0..511
  kw2p[idx] = pkf16(kW2[(size_t)(2 * p) * HH + col],
                    kW2[(size_t)(2 * p + 1) * HH + col]);
}

// ---------------------------------------------------------------------------
// Persistent scan: 512 WGs x 256 thr, 52 KB static LDS.
// ---------------------------------------------------------------------------
__global__ __launch_bounds__(256)
void scan_kernel(const float* __restrict__ gx,
                 const float* __restrict__ Whh, const float* __restrict__ bhh,
                 const float* __restrict__ loglam,
                 const float* __restrict__ kW1, const float* __restrict__ kb1,
                 const u32* __restrict__ kw2p, const float* __restrict__ kb2,
                 u32* __restrict__ cpk, u32* __restrict__ ipk,
                 u32* __restrict__ kpk, u32* __restrict__ tags,
                 float* __restrict__ hs)
{
  const int blk  = blockIdx.x;
  const int g    = blk & 7;         // group (rows 4g..4g+3)
  const int s    = blk >> 3;        // slot 0..63
  const int tid  = threadIdx.x;
  const int q    = tid >> 6;        // wave 0..3
  const int lane = tid & 63;
  const int jz   = s * 8;
  const int jm   = s * 24;

  __shared__ u32 wh[16 * 256];      // 16 KB: 8 z-cols + 8 m-cols, f16 pairs
  __shared__ u32 w1s[24 * 256];     // 24 KB
  __shared__ u32 stg[4 * 768];      // 12 KB comm staging (c/innov use 1/3)

  // ---- one-time weight staging (fp32 -> f16 pairs) ----
  for (int idx = tid; idx < 16 * 256; idx += 256) {
    int c = idx >> 8, p = idx & 255;
    int gcol = (c < 8) ? (jz + c) : (512 + jz + (c - 8));
    wh[idx] = pkf16(Whh[(size_t)(2 * p) * G2H + gcol],
                    Whh[(size_t)(2 * p + 1) * G2H + gcol]);
  }
  for (int idx = tid; idx < 24 * 256; idx += 256) {
    int c = idx >> 8, p = idx & 255;
    w1s[idx] = pkf16(kW1[(size_t)(2 * p) * K3H + jm + c],
                     kW1[(size_t)(2 * p + 1) * K3H + jm + c]);
  }

  // per-lane constants (state mapping: r=lane>>1, ci=lane&1, valid lanes<8)
  const int colA = jz + 2 * q + (lane & 1);
  const float Ab   = 1.f - expf(loglam[colA]);
  const float bz   = bhh[colA];
  const float bm   = bhh[512 + colA];
  const float kb2c = kb2[colA];
  int kb1i = lane & 7; if (kb1i > 5) kb1i = 5;
  const float kb1v = kb1[jm + 6 * q + kb1i];

  const int r_st  = (lane >> 1) & 3;
  const int growst = 4 * g + r_st;
  const size_t hsoff = (size_t)growst * LSEQ * HH + colA;
  const size_t gxoff = (size_t)growst * LSEQ * G2H + colA;

  u32* tgg = tags + g * GWG;

  // zero this WG's initial c slice, then publish tag gen 1
  if (tid < 16) {
    int r = tid >> 2, j = tid & 3;
    mstore(cpk + (size_t)(4 * g + r) * 256 + 4 * s + j, 0u);
  }
  publish_fence();
  if (tid == 0) mstore(tgg + s, 1u);

  float A_own = 0.f, c_own = 0.f, M_own = 0.f, I_own = 0.f, s_own = 1.f;

  for (int it = 0; it <= LSEQ; ++it) {
    const u32 base = 3u * (u32)it;

    // gx prefetch (cached, read-once; independent of polls)
    float gxz = 0.f, gxm = 0.f;
    if (lane < 8 && it < LSEQ) {
      gxz = gx[gxoff + (size_t)it * G2H];
      gxm = gx[gxoff + (size_t)it * G2H + 512];
    }

    // ---- S1: wait c(it) -> stage -> s, g = h@W_hh, innov ----
    poll16(tgg, base + 1, tid);
    {
      int row = tid >> 6, off = (tid & 63) * 4;
      v4u t; mload4(t, cpk + (size_t)(4 * g + row) * 256 + off);
      vmwait(t);
      *(v4u*)(stg + row * 256 + off) = t;
    }
    __syncthreads();
    v4u cv0 = *(const v4u*)(stg + 0 * 256 + lane * 4);
    v4u cv1 = *(const v4u*)(stg + 1 * 256 + lane * 4);
    v4u cv2 = *(const v4u*)(stg + 2 * 256 + lane * 4);
    v4u cv3 = *(const v4u*)(stg + 3 * 256 + lane * 4);
    float a4[4] = { dotq(cv0, cv0, 0.f), dotq(cv1, cv1, 0.f),
                    dotq(cv2, cv2, 0.f), dotq(cv3, cv3, 0.f) };
    float a16[16];
#pragma unroll
    for (int t = 0; t < 4; ++t) {          // t<2: z col 2q+t ; t>=2: m col
      int col = (t < 2) ? (2 * q + t) : (8 + 2 * q + (t - 2));
      v4u wq = *(const v4u*)(wh + col * 256 + lane * 4);
      a16[0 * 4 + t] = dotq(cv0, wq, 0.f);
      a16[1 * 4 + t] = dotq(cv1, wq, 0.f);
      a16[2 * 4 + t] = dotq(cv2, wq, 0.f);
      a16[3 * 4 + t] = dotq(cv3, wq, 0.f);
    }
    float ssv = tree_reduce<4>(a4, lane);     // row = lane&3
    float g16 = tree_reduce<16>(a16, lane);   // (r=(lane&15)>>2, t=lane&3)
    float sq  = __shfl(ssv, r_st, 64);
    float s_loc = fminf(1.f, 10.f * rsqrtf(sq + 1e-6f));
    float gz = __shfl(g16, (r_st * 4 + (lane & 1)) & 63, 64);
    float gm = __shfl(g16, (r_st * 4 + 2 + (lane & 1)) & 63, 64);
    if (lane < 8 && it >= 1)
      hs[hsoff + (size_t)(it - 1) * HH] = s_loc * c_own;
    if (it == LSEQ) break;
    float gzv = gz * s_loc + gxz + bz;
    float gmv = gm * s_loc + gxm + bm;
    float Mv = tanhf(gmv);
    float iv = gzv - A_own * (s_loc * c_own) - Mv;
    if (lane < 8) { M_own = Mv; I_own = iv; s_own = s_loc; }
    float ivn = __shfl(iv, (lane + 1) & 63, 64);
    if (lane < 8 && !(lane & 1))
      mstore(ipk + (size_t)growst * 256 + 4 * s + q, pkf16(iv, ivn));
    publish_fence();
    if (tid == 0) mstore(tgg + s, base + 2);

    // ---- S2: wait innov -> stage -> kmid = gelu(innov @ kW1 + kb1) ----
    poll16(tgg, base + 2, tid);
    {
      int row = tid >> 6, off = (tid & 63) * 4;
      v4u t; mload4(t, ipk + (size_t)(4 * g + row) * 256 + off);
      vmwait(t);
      *(v4u*)(stg + row * 256 + off) = t;
    }
    __syncthreads();
    v4u iv0 = *(const v4u*)(stg + 0 * 256 + lane * 4);
    v4u iv1 = *(const v4u*)(stg + 1 * 256 + lane * 4);
    v4u iv2 = *(const v4u*)(stg + 2 * 256 + lane * 4);
    v4u iv3 = *(const v4u*)(stg + 3 * 256 + lane * 4);
    float a32[32];
#pragma unroll
    for (int i = 0; i < 32; ++i) a32[i] = 0.f;
#pragma unroll
    for (int cc = 0; cc < 6; ++cc) {
      v4u wq = *(const v4u*)(w1s + (6 * q + cc) * 256 + lane * 4);
      a32[0 * 8 + cc] = dotq(iv0, wq, 0.f);
      a32[1 * 8 + cc] = dotq(iv1, wq, 0.f);
      a32[2 * 8 + cc] = dotq(iv2, wq, 0.f);
      a32[3 * 8 + cc] = dotq(iv3, wq, 0.f);
    }
    float t32 = tree_reduce<32>(a32, lane);   // (r=(lane&31)>>3, cc=lane&7)
    float kvb = t32 + kb1v;
    float gl = 0.5f * kvb * (1.f + erff(kvb * 0.7071067811865476f));
    float gln = __shfl(gl, (lane + 1) & 63, 64);
    if (lane < 32 && !(lane & 1) && (lane & 7) < 6) {
      int rr = (lane >> 3) & 3, cc = lane & 7;
      mstore(kpk + (size_t)(4 * g + rr) * 768 + 12 * s + 3 * q + (cc >> 1),
             pkf16(gl, gln));
    }
    publish_fence();
    if (tid == 0) mstore(tgg + s, base + 3);

    // ---- S3: wait kmid -> stage -> K = tanh(kmid @ kW2 + kb2)*0.5 ; c ----
    poll16(tgg, base + 3, tid);
    {
      int row = tid >> 6, off = (tid & 63) * 4;
      const u32* src = kpk + (size_t)(4 * g + row) * 768 + off;
      v4u t0, t1, t2;
      mload4(t0, src); mload4(t1, src + 256); mload4(t2, src + 512);
      vmwait(t0); vmwait(t1); vmwait(t2);
      u32* dst = stg + row * 768 + off;
      *(v4u*)dst = t0; *(v4u*)(dst + 256) = t1; *(v4u*)(dst + 512) = t2;
    }
    __syncthreads();
    v4u kv[4][3];
#pragma unroll
    for (int r = 0; r < 4; ++r)
#pragma unroll
      for (int j = 0; j < 3; ++j)
        kv[r][j] = *(const v4u*)(stg + r * 768 + j * 256 + lane * 4);
    const u32* kw2b = kw2p + (size_t)(8 * s + 2 * q) * 768;
    float a8[8];
#pragma unroll
    for (int ci = 0; ci < 2; ++ci) {
      v4u wq0 = *(const v4u*)(kw2b + ci * 768 + 0   + lane * 4);
      v4u wq1 = *(const v4u*)(kw2b + ci * 768 + 256 + lane * 4);
      v4u wq2 = *(const v4u*)(kw2b + ci * 768 + 512 + lane * 4);
#pragma unroll
      for (int r = 0; r < 4; ++r)
        a8[r * 2 + ci] = dotq(kv[r][2], wq2,
                         dotq(kv[r][1], wq1,
                         dotq(kv[r][0], wq0, 0.f)));
    }
    float kr = tree_reduce<8>(a8, lane);   // (r=(lane&7)>>1, ci=lane&1)
    float Kv = tanhf(kr + kb2c) * 0.5f;
    float An = Ab * (1.f - Kv * Kv);
    float cn = An * (s_own * c_own) + Kv * I_own + M_own;
    if (lane < 8) { A_own = An; c_own = cn; }
    float cnn = __shfl(cn, (lane + 1) & 63, 64);
    if (lane < 8 && !(lane & 1))
      mstore(cpk + (size_t)growst * 256 + 4 * s + q, pkf16(cn, cnn));
    publish_fence();
    if (tid == 0) mstore(tgg + s, base + 4);
  }
}

// ---------------------------------------------------------------------------
// Workspace layout (bytes):
//   [0, 32M)    xn (reused as hs)
//   [32M, 96M)  gx
//   [96M,128M)  xmid  (first 1.5MB doubles as kw2p — dead during scans)
//   [128M, ..)  cpk 32K | ipk 32K | kpk 96K | tags 2K
// ---------------------------------------------------------------------------
extern "C" void kernel_launch(void* const* d_in, const int* in_sizes, int n_in,
                              void* d_out, int out_size, void* d_ws, size_t ws_size,
                              hipStream_t stream) {
  const float* x      = (const float*)d_in[0];
  const float* norm_w = (const float*)d_in[1];
  const float* W_ih   = (const float*)d_in[2];
  const float* b_ih   = (const float*)d_in[3];
  const float* W_hh   = (const float*)d_in[4];
  const float* b_hh   = (const float*)d_in[5];
  const float* loglam = (const float*)d_in[6];
  const float* kW1    = (const float*)d_in[7];
  const float* kb1    = (const float*)d_in[8];
  const float* kW2    = (const float*)d_in[9];
  const float* kb2    = (const float*)d_in[10];
  const float* Wo     = (const float*)d_in[11];
  float* out = (float*)d_out;

  char* ws = (char*)d_ws;
  float* xn   = (float*)(ws);
  float* gxb  = (float*)(ws + (size_t)33554432);
  float* xmid = (float*)(ws + (size_t)100663296);
  u32* kw2p  = (u32*)xmid;              // 1.5MB, dead region during scans
  u32* cpk   = (u32*)(ws + (size_t)134217728);
  u32* ipk   = cpk + 8192;
  u32* kpk   = ipk + 8192;
  u32* tags  = kpk + 24576;             // 512 u32
  float* hs = xn;

  for (int l = 0; l < 2; ++l) {
    const float* xin = l ? (const float*)xmid : x;
    float* cout = l ? out : xmid;

    rmsnorm_kernel<<<BB * LSEQ, 256, 0, stream>>>(xin, norm_w, xn);

    gemm_fp32<<<dim3(256, 16), 256, 0, stream>>>(
        xn, W_ih + (size_t)l * DD * G2H, b_ih + (size_t)l * G2H, gxb,
        BB * LSEQ, G2H, DD);

    hipMemsetAsync(tags, 0, NG * GWG * sizeof(u32), stream);
    pack_kw2<<<1536, 256, 0, stream>>>(kW2 + (size_t)l * K3H * HH, kw2p);

    scan_kernel<<<NG * GWG, 256, 0, stream>>>(
        gxb,
        W_hh + (size_t)l * HH * G2H, b_hh + (size_t)l * G2H,
        loglam + (size_t)l * HH,
        kW1 + (size_t)l * HH * K3H, kb1 + (size_t)l * K3H,
        kw2p, kb2 + (size_t)l * HH,
        cpk, ipk, kpk, tags, hs);

    gemm_fp32<<<dim3(256, 8), 256, 0, stream>>>(
        hs, Wo + (size_t)l * HH * DD, nullptr, cout,
        BB * LSEQ, DD, HH);
  }
}